// Round 9
// baseline (161.871 us; speedup 1.0000x reference)
//
#include <hip/hip_runtime.h>

#define HS 128
#define DM 1024
#define BB 8
#define TT 2048

typedef __bf16 bf16;
typedef __bf16 bf16x8 __attribute__((ext_vector_type(8)));
typedef float f32x4 __attribute__((ext_vector_type(4)));

#define MFMA16(a, b, c) __builtin_amdgcn_mfma_f32_16x16x32_bf16(a, b, c, 0, 0, 0)
// raw barrier: does NOT drain vmcnt (unlike __syncthreads) — loads stay in flight
#define RAW_BARRIER() asm volatile("s_barrier" ::: "memory")

__device__ __forceinline__ void gll16(const bf16* g, bf16* l) {
  __builtin_amdgcn_global_load_lds(
      (const __attribute__((address_space(1))) void*)g,
      (__attribute__((address_space(3))) void*)l, 16, 0, 0);
}
__device__ __forceinline__ void gll16f(const float* g, float* l) {
  __builtin_amdgcn_global_load_lds(
      (const __attribute__((address_space(1))) void*)g,
      (__attribute__((address_space(3))) void*)l, 16, 0, 0);
}

// ---------------- W transpose: Wt[mat*128+h][k] = W[k][h], fp32 -> bf16 -----
__global__ __launch_bounds__(256) void wt_kernel(const float* __restrict__ Wq,
                                                 const float* __restrict__ Wk,
                                                 const float* __restrict__ Wv,
                                                 bf16* __restrict__ Wt) {
  __shared__ bf16 lt[128][72];
  const int mat = blockIdx.y;
  const float* W = mat == 0 ? Wq : (mat == 1 ? Wk : Wv);
  const int k0 = blockIdx.x * 64;
  const int t = threadIdx.x;
  for (int i = 0; i < 32; ++i) {
    int idx = t + i * 256;
    int k = idx >> 7;
    int h = idx & 127;
    lt[h][k] = (bf16)W[(size_t)(k0 + k) * HS + h];
  }
  __syncthreads();
  int h = t >> 1, half = t & 1;
  const uint4* src = (const uint4*)&lt[h][half * 32];
  uint4* dst = (uint4*)(Wt + ((size_t)mat * 128 + h) * DM + k0 + half * 32);
  dst[0] = src[0]; dst[1] = src[1]; dst[2] = src[2]; dst[3] = src[3];
}

// ---------------- fused QKV GEMM + V-transpose epilogue ---------------------
// R17: THREE resident gll-staged blocks per CU. Unified R8-R16 model: each
// gll-staged block is a latency-serialized chain delivering ~6.4 B/cyc;
// resident blocks hide each other (1 blk=8.7, 2 blk=12.7, m97 3-4 blk=22
// B/cyc/CU). Every in-block trick failed; resident count was never cleanly
// tested (R12 = flat-load confound, R9/R10 = quad-buf conflict confound).
// grid 768 = 256 row-tiles(64) x 3 matrix-blocks (nb0=Q,1=K,2=V; R12-proven
// mapping + XCD swizzle). 256 thr / 4 waves, wave-tile 32x64, BK=32, dbuf.
// LDS 32 KB/block -> 3 blocks/CU resident (12 waves/CU).
// Staging: 4 gll/wave/step (2 x + 2 W); steady vmcnt(4), tail vmcnt(0).
// x LDS [64r][32k] f32 (128B rows): slot u holds global f4-chunk u^(row&7);
//   read c -> slot c^(ar&7): per quad 2 lanes/slot in DIFFERENT rows = free.
// W LDS paired-lines [64L][64k] bf16: slot u_phys=((q<<1)|(r&1))^(L&7);
//   read: 2 lanes/slot-index in different lines = free. gll sources carry
//   the inverse permutation (both-sides-or-neither).
__global__ __launch_bounds__(256) void qkv_kernel(const float* __restrict__ x,
                                                  const bf16* __restrict__ Wt,
                                                  bf16* __restrict__ Q,
                                                  bf16* __restrict__ K,
                                                  bf16* __restrict__ Vt) {
  __shared__ __align__(16) char qsm[32768];
  float* xsf = (float*)qsm;             // 2 x [64r][32k] f32 = 16 KB
  bf16* wsb = (bf16*)(qsm + 16384);     // 2 x [64 lines][64k] bf16 = 16 KB
  bf16* vts = (bf16*)qsm;  // epilogue overlay (nb==2): [128 h][72] bf16, 18 KB
  const int t = threadIdx.x, w = t >> 6, lane = t & 63, rl = lane & 15, quad = lane >> 4;
  const int g = blockIdx.x;
  const int wgid = (g & 7) * 96 + (g >> 3);  // XCD-bijective: 96 blocks/XCD
  const int rt = wgid / 3, nb = wgid - rt * 3;
  const int row0 = rt * 64;
  const int rw = w & 1, cw = w >> 1;  // wave tile: 32 rows x 64 cols
  const int l3 = lane >> 3, l7 = lane & 7, e = l7 ^ l3;
  f32x4 acc[2][4] = {};

  auto stage = [&](int kt, int bufi) {
#pragma unroll
    for (int i2 = 0; i2 < 2; ++i2) {  // x: 8 segs of 8 rows x 32 f32
      int s = w * 2 + i2;
      int row = s * 8 + l3;
      gll16f(x + (size_t)(row0 + row) * DM + kt * 32 + e * 4,
             xsf + bufi * 2048 + s * 256);
    }
#pragma unroll
    for (int i2 = 0; i2 < 2; ++i2) {  // W: 8 segs of 8 lines (16 logical rows)
      int s = w * 2 + i2;
      int L = s * 8 + l3;
      int r = 2 * L + (e & 1);
      gll16(Wt + (size_t)(nb * 128 + r) * DM + kt * 32 + (e >> 1) * 8,
            wsb + bufi * 4096 + s * 512);
    }
  };

  stage(0, 0);
  stage(1, 1);
  for (int kt = 0; kt < 32; ++kt) {
    const int cur = kt & 1;
    // queue: stage(kt)[4] + stage(kt+1)[4]; vmcnt(4) -> stage(kt) landed
    if (kt < 31) asm volatile("s_waitcnt vmcnt(4)" ::: "memory");
    else         asm volatile("s_waitcnt vmcnt(0)" ::: "memory");
    RAW_BARRIER();  // stage(kt) landed block-wide; stage(kt+1) keeps flying
    const float* xc = xsf + cur * 2048;
    const bf16* wc = wsb + cur * 4096;
    bf16x8 a[2];
#pragma unroll
    for (int rf = 0; rf < 2; ++rf) {
      int ar = rw * 32 + rf * 16 + rl;
      int c0 = quad * 2;
      float4 f0 = *(const float4*)&xc[ar * 32 + (((c0) ^ (ar & 7)) << 2)];
      float4 f1 = *(const float4*)&xc[ar * 32 + (((c0 + 1) ^ (ar & 7)) << 2)];
      bf16x8 tv;
      tv[0] = (bf16)f0.x; tv[1] = (bf16)f0.y; tv[2] = (bf16)f0.z; tv[3] = (bf16)f0.w;
      tv[4] = (bf16)f1.x; tv[5] = (bf16)f1.y; tv[6] = (bf16)f1.z; tv[7] = (bf16)f1.w;
      a[rf] = tv;
    }
#pragma unroll
    for (int cf = 0; cf < 4; ++cf) {
      int br = cw * 64 + cf * 16 + rl;
      int L = br >> 1;
      int up = ((quad << 1) | (br & 1)) ^ (L & 7);
      bf16x8 bb = *(const bf16x8*)&wc[L * 64 + (up << 3)];
      acc[0][cf] = MFMA16(a[0], bb, acc[0][cf]);
      acc[1][cf] = MFMA16(a[1], bb, acc[1][cf]);
    }
    RAW_BARRIER();  // all waves done reading buf[cur]
    if (kt < 30) stage(kt + 2, cur);
  }
  // epilogue: whole block is one matrix (nb) — R12-proven
  if (nb < 2) {
    bf16* dst = nb == 0 ? Q : K;
#pragma unroll
    for (int cf = 0; cf < 4; ++cf) {
      int hcol = cw * 64 + cf * 16 + rl;
#pragma unroll
      for (int rf = 0; rf < 2; ++rf)
#pragma unroll
        for (int r = 0; r < 4; ++r) {
          int tg = row0 + rw * 32 + rf * 16 + quad * 4 + r;
          dst[((size_t)tg << 7) + hcol] = (bf16)acc[rf][cf][r];
        }
    }
  } else {  // V: LDS transpose overlay (staging buffers dead), write Vt[b][h][t]
    __syncthreads();  // all waves done with staging LDS before overlay
#pragma unroll
    for (int cf = 0; cf < 4; ++cf) {
      int hcol = cw * 64 + cf * 16 + rl;
#pragma unroll
      for (int rf = 0; rf < 2; ++rf)
#pragma unroll
        for (int r = 0; r < 4; ++r) {
          int trow = rw * 32 + rf * 16 + quad * 4 + r;  // 0..63
          vts[hcol * 72 + trow] = (bf16)acc[rf][cf][r];
        }
    }
    __syncthreads();
    const int h = t >> 1, half = t & 1;
    const bf16* src = vts + h * 72 + half * 32;
    bf16* dst = Vt + ((size_t)((row0 >> 11) * 128 + h) << 11) + (row0 & 2047) + half * 32;
#pragma unroll
    for (int j = 0; j < 4; ++j)
      ((bf16x8*)dst)[j] = ((const bf16x8*)src)[j];
  }
}

// ---------------- flash attention (R8 + Q-hoist + R14 load balance) ---------
// grid 512, 256 thr; 32 q-rows/block; shared 64-wide K/V tile; waves = 2
// row-halves x 2 k-col-halves; 77KB LDS -> 2 blocks/CU; dbuf + raw-barrier +
// vmcnt(8). Q frags preloaded into 16 VGPRs at i==0.
// R14: balanced CU pairing. Causal work KT(qi)=qi/2+1; r<32 -> qi=63-r,
// r>=32 -> qi=r-32 pairs long+short -> every CU carries ~33.5 k-tiles.
__global__ __launch_bounds__(256) void attn_kernel(const bf16* __restrict__ Qb,
                                                   const bf16* __restrict__ Kb,
                                                   const bf16* __restrict__ Vtb,
                                                   float* __restrict__ out) {
  __shared__ __align__(16) char smem[79104];
  bf16* qs = (bf16*)smem;
  bf16* ks = (bf16*)(smem + 8192);
  bf16* vt = (bf16*)(smem + 40960);
  float* Of = (float*)smem;             // epilogue overlay: 2 x 32 x 128 f32
  float* ml = (float*)(smem + 78848);   // 64 f32
  const int t = threadIdx.x, w = t >> 6, lane = t & 63, rl = lane & 15, quad = lane >> 4;
  const int wrow = w >> 1, kh = w & 1;
  const int rank = blockIdx.x >> 3, b = blockIdx.x & 7;
  const int qi = (rank < 32) ? (63 - rank) : (rank - 32);
  const int q0 = qi * 32;
  const size_t base = (size_t)b * TT;
  const int KT = (qi >> 1) + 1;  // 64-wide k-tiles

#pragma unroll
  for (int i2 = 0; i2 < 2; ++i2) {  // stage Q (32 x 128): 2 gll/wave
    int s = w * 2 + i2;
    int row = s * 4 + (lane >> 4);
    int ch = (lane & 15) ^ (row & 15);
    gll16(Qb + ((base + q0 + row) << 7) + ch * 8, qs + s * 512);
  }
  auto stageKV = [&](int slot) {  // always 8 gll/wave (clamped) for exact vmcnt
    int kt = min(slot, KT - 1);
    int bufi = slot & 1;
    bf16* ksb = ks + bufi * 8192;
    bf16* vtb = vt + bufi * 8192;
#pragma unroll
    for (int i2 = 0; i2 < 4; ++i2) {
      int s = w * 4 + i2;
      int rowk = s * 4 + (lane >> 4);
      int chk = (lane & 15) ^ (rowk & 15);
      gll16(Kb + ((base + kt * 64 + rowk) << 7) + chk * 8, ksb + s * 512);
      int rowv = s * 8 + (lane >> 3);
      int chv = (lane & 7) ^ (rowv & 7);
      gll16(Vtb + ((size_t)(b * 128 + rowv) << 11) + kt * 64 + chv * 8, vtb + s * 512);
    }
  };
  stageKV(0);
  stageKV(1);

  f32x4 o[8] = {};
  float lrow[4] = {0.f, 0.f, 0.f, 0.f};
  bf16x8 aq[4];  // loop-invariant Q fragments (hoisted at i==0)
  bf16* psw = (bf16*)(smem + 73728) + w * 640;  // [16][40] per wave

  for (int i = 0; i < KT; ++i) {
    const int cur = i & 1;
    asm volatile("s_waitcnt vmcnt(8)" ::: "memory");
    RAW_BARRIER();
    if (i == 0) {
      const int arow = wrow * 16 + rl;
#pragma unroll
      for (int hc = 0; hc < 4; ++hc)
        aq[hc] = *(const bf16x8*)(qs + arow * 128 + ((((hc << 2) + quad) ^ (arow & 15)) << 3));
    }
    bf16* ksb = ks + cur * 8192;
    bf16* vtb = vt + cur * 8192;
    f32x4 s4[2] = {};
#pragma unroll
    for (int hc = 0; hc < 4; ++hc) {
#pragma unroll
      for (int c = 0; c < 2; ++c) {
        int brow = (kh * 2 + c) * 16 + rl;
        bf16x8 bb = *(const bf16x8*)(ksb + brow * 128 + ((((hc << 2) + quad) ^ (brow & 15)) << 3));
        s4[c] = MFMA16(aq[hc], bb, s4[c]);
      }
    }
    const bool diag = (i == KT - 1);
#pragma unroll
    for (int r = 0; r < 4; ++r) {
      int rloc = quad * 4 + r;
      int rowg = q0 + wrow * 16 + rloc;
      float psum = 0.f;
#pragma unroll
      for (int c = 0; c < 2; ++c) {
        int colg = i * 64 + kh * 32 + c * 16 + rl;
        // fixed-max softmax: scores ~ N(0,~0.6); m=6 is a safe upper bound
        float p = (diag && colg > rowg) ? 0.f : __expf(s4[c][r] * 0.03125f - 6.0f);
        psum += p;
        psw[rloc * 40 + c * 16 + rl] = (bf16)p;
      }
      lrow[r] += psum;
    }
    bf16x8 pa = *(const bf16x8*)(psw + rl * 40 + quad * 8);
#pragma unroll
    for (int ht = 0; ht < 8; ++ht) {
      int brow = ht * 16 + rl;
      bf16x8 bb = *(const bf16x8*)(vtb + brow * 64 + ((((kh << 2) + quad) ^ (brow & 7)) << 3));
      o[ht] = MFMA16(pa, bb, o[ht]);
    }
    RAW_BARRIER();  // all waves done reading buf[cur]
    if (i + 2 <= KT) stageKV(i + 2);
  }

#pragma unroll
  for (int r = 0; r < 4; ++r)
#pragma unroll
    for (int off = 1; off < 16; off <<= 1) lrow[r] += __shfl_xor(lrow[r], off, 64);
  __syncthreads();  // full drain (incl leftover clamped gll); overlay safe
#pragma unroll
  for (int ht = 0; ht < 8; ++ht)
#pragma unroll
    for (int r = 0; r < 4; ++r)
      Of[kh * 4096 + (wrow * 16 + quad * 4 + r) * 128 + ht * 16 + rl] = o[ht][r];
  if (rl == 0)
#pragma unroll
    for (int r = 0; r < 4; ++r) ml[kh * 32 + wrow * 16 + quad * 4 + r] = lrow[r];
  __syncthreads();
#pragma unroll
  for (int r = 0; r < 4; ++r) {
    int rowl = wrow * 16 + quad * 4 + r;
    float inv = 1.f / (ml[rowl] + ml[32 + rowl]);
#pragma unroll
    for (int hh = 0; hh < 4; ++hh) {
      int col = kh * 64 + hh * 16 + rl;
      out[((base + q0 + rowl) << 7) + col] =
          (Of[rowl * 128 + col] + Of[4096 + rowl * 128 + col]) * inv;
    }
  }
}

extern "C" void kernel_launch(void* const* d_in, const int* in_sizes, int n_in,
                              void* d_out, int out_size, void* d_ws, size_t ws_size,
                              hipStream_t stream) {
  const float* x = (const float*)d_in[0];
  const float* Wq = (const float*)d_in[1];
  const float* Wk = (const float*)d_in[2];
  const float* Wv = (const float*)d_in[3];
  float* out = (float*)d_out;
  char* ws = (char*)d_ws;
  // ws: Wt 768KB | Q 4MB | K 4MB | Vt 4MB  (13.4 MB total)
  bf16* Wt = (bf16*)ws;
  bf16* Q = (bf16*)(ws + 786432);
  bf16* K = (bf16*)(ws + 786432 + 4194304);
  bf16* Vt = (bf16*)(ws + 786432 + 2 * 4194304);
  wt_kernel<<<dim3(16, 3), 256, 0, stream>>>(Wq, Wk, Wv, Wt);
  qkv_kernel<<<dim3(768), 256, 0, stream>>>(x, Wt, Q, K, Vt);
  attn_kernel<<<dim3(512), 256, 0, stream>>>(Q, K, Vt, out);
}

// Round 10
// 150.430 us; speedup vs baseline: 1.0761x; 1.0761x over previous
//
#include <hip/hip_runtime.h>

#define HS 128
#define DM 1024
#define BB 8
#define TT 2048

typedef __bf16 bf16;
typedef __bf16 bf16x8 __attribute__((ext_vector_type(8)));
typedef float f32x4 __attribute__((ext_vector_type(4)));

#define MFMA16(a, b, c) __builtin_amdgcn_mfma_f32_16x16x32_bf16(a, b, c, 0, 0, 0)
// raw barrier: does NOT drain vmcnt (unlike __syncthreads) — loads stay in flight
#define RAW_BARRIER() asm volatile("s_barrier" ::: "memory")

__device__ __forceinline__ void gll16(const bf16* g, bf16* l) {
  __builtin_amdgcn_global_load_lds(
      (const __attribute__((address_space(1))) void*)g,
      (__attribute__((address_space(3))) void*)l, 16, 0, 0);
}
__device__ __forceinline__ void gll16f(const float* g, float* l) {
  __builtin_amdgcn_global_load_lds(
      (const __attribute__((address_space(1))) void*)g,
      (__attribute__((address_space(3))) void*)l, 16, 0, 0);
}

// ---------------- W transpose: Wt[mat*128+h][k] = W[k][h], fp32 -> bf16 -----
__global__ __launch_bounds__(256) void wt_kernel(const float* __restrict__ Wq,
                                                 const float* __restrict__ Wk,
                                                 const float* __restrict__ Wv,
                                                 bf16* __restrict__ Wt) {
  __shared__ bf16 lt[128][72];
  const int mat = blockIdx.y;
  const float* W = mat == 0 ? Wq : (mat == 1 ? Wk : Wv);
  const int k0 = blockIdx.x * 64;
  const int t = threadIdx.x;
  for (int i = 0; i < 32; ++i) {
    int idx = t + i * 256;
    int k = idx >> 7;
    int h = idx & 127;
    lt[h][k] = (bf16)W[(size_t)(k0 + k) * HS + h];
  }
  __syncthreads();
  int h = t >> 1, half = t & 1;
  const uint4* src = (const uint4*)&lt[h][half * 32];
  uint4* dst = (uint4*)(Wt + ((size_t)mat * 128 + h) * DM + k0 + half * 32);
  dst[0] = src[0]; dst[1] = src[1]; dst[2] = src[2]; dst[3] = src[3];
}

// ---------------- fused QKV GEMM + V-transpose epilogue ---------------------
// R18 = R14 verbatim (session best, 151.59 us total; qkv 42.1 us).
// Family floor derivation (R8-R17): gll delivery saturates at ~12.7 B/cyc/CU
// for >=2 resident blocks (R8 2/CU: 12.7; R17 3/CU: 12.65) and drops to ~8.5
// at 1/CU (R11/R13). Time = staged_bytes/12.7; this geometry's 320 MB is the
// minimum reachable under the >=2-blocks constraint -> 41 us floor ~= measured.
// grid 512 = 256 row-tiles(64) x 2 col-halves(192) -> 2 blocks/CU (80 KB LDS).
// 256 thr, wave-tile 32x96, BK=64, dbuf, raw-barrier + vmcnt(10). V accums
// go through an 18 KB LDS transpose overlay and are written as Vt[b][h][t].
__global__ __launch_bounds__(256) void qkv_kernel(const float* __restrict__ x,
                                                  const bf16* __restrict__ Wt,
                                                  bf16* __restrict__ Q,
                                                  bf16* __restrict__ K,
                                                  bf16* __restrict__ Vt) {
  __shared__ __align__(16) char qsm[81920];
  float (*xsf)[4096] = (float(*)[4096])qsm;            // 2 x 64rows x 64k fp32, XOR-16
  bf16 (*wsb)[12288] = (bf16(*)[12288])(qsm + 32768);  // 2 x 192rows x 64k bf16, XOR-8
  bf16* vts = (bf16*)qsm;  // epilogue overlay: [128 h][72] (stride-72: 2-way free)
  const int t = threadIdx.x, w = t >> 6, lane = t & 63, rl = lane & 15, quad = lane >> 4;
  const int rt = blockIdx.x >> 1, nb = blockIdx.x & 1;
  const int row0 = rt * 64;
  const int rw = w & 1, cw = w >> 1;  // wave tile: 32 rows x 96 cols
  f32x4 acc[2][6] = {};

  auto stage = [&](int kt, int bufi) {
#pragma unroll
    for (int i2 = 0; i2 < 4; ++i2) {  // x: 16 segs of 4 rows x 64 fp32
      int s = w * 4 + i2;
      int row = s * 4 + (lane >> 4);
      int cg = (lane & 15) ^ (row & 15);
      gll16f(x + (size_t)(row0 + row) * DM + kt * 64 + cg * 4, &xsf[bufi][s * 256]);
    }
#pragma unroll
    for (int i2 = 0; i2 < 6; ++i2) {  // W: 24 segs of 8 rows x 64 bf16
      int s = w * 6 + i2;
      int row = s * 8 + (lane >> 3);
      int cg = (lane & 7) ^ (row & 7);
      gll16(Wt + (size_t)(nb * 192 + row) * DM + kt * 64 + cg * 8, &wsb[bufi][s * 512]);
    }
  };

  stage(0, 0);
  stage(1, 1);
  for (int kt = 0; kt < 16; ++kt) {
    const int cur = kt & 1;
    if (kt < 15) asm volatile("s_waitcnt vmcnt(10)" ::: "memory");
    else         asm volatile("s_waitcnt vmcnt(0)" ::: "memory");
    RAW_BARRIER();  // stage(kt) landed block-wide; stage(kt+1) keeps flying
#pragma unroll
    for (int kc = 0; kc < 2; ++kc) {
      bf16x8 a[2];
#pragma unroll
      for (int rf = 0; rf < 2; ++rf) {
        int ar = rw * 32 + rf * 16 + rl;
        int c0 = kc * 8 + quad * 2;
        float4 f0 = *(const float4*)&xsf[cur][ar * 64 + (((c0) ^ (ar & 15)) << 2)];
        float4 f1 = *(const float4*)&xsf[cur][ar * 64 + (((c0 + 1) ^ (ar & 15)) << 2)];
        bf16x8 tv;
        tv[0] = (bf16)f0.x; tv[1] = (bf16)f0.y; tv[2] = (bf16)f0.z; tv[3] = (bf16)f0.w;
        tv[4] = (bf16)f1.x; tv[5] = (bf16)f1.y; tv[6] = (bf16)f1.z; tv[7] = (bf16)f1.w;
        a[rf] = tv;
      }
#pragma unroll
      for (int cf = 0; cf < 6; ++cf) {
        int br = cw * 96 + cf * 16 + rl;
        int cb = kc * 4 + quad;
        bf16x8 bb = *(const bf16x8*)&wsb[cur][br * 64 + ((cb ^ (br & 7)) << 3)];
        acc[0][cf] = MFMA16(a[0], bb, acc[0][cf]);
        acc[1][cf] = MFMA16(a[1], bb, acc[1][cf]);
      }
    }
    RAW_BARRIER();  // all waves done reading buf[cur]
    if (kt < 14) stage(kt + 2, cur);
  }
  // epilogue: Q/K straight to global; V into LDS transpose (nb==1 only)
#pragma unroll
  for (int cf = 0; cf < 6; ++cf) {
    int cg = nb * 192 + cw * 96 + cf * 16 + rl;  // uniform mat per (cw,cf)
    int mat = cg >> 7, hcol = cg & 127;
    if (mat < 2) {
      bf16* dst = mat == 0 ? Q : K;
#pragma unroll
      for (int rf = 0; rf < 2; ++rf)
#pragma unroll
        for (int r = 0; r < 4; ++r) {
          int tg = row0 + rw * 32 + rf * 16 + quad * 4 + r;
          dst[((size_t)tg << 7) + hcol] = (bf16)acc[rf][cf][r];
        }
    } else {
#pragma unroll
      for (int rf = 0; rf < 2; ++rf)
#pragma unroll
        for (int r = 0; r < 4; ++r) {
          int trow = rw * 32 + rf * 16 + quad * 4 + r;
          vts[hcol * 72 + trow] = (bf16)acc[rf][cf][r];
        }
    }
  }
  if (nb == 1) {  // block-uniform
    __syncthreads();
    const int h = t >> 1, half = t & 1;
    const bf16* src = vts + h * 72 + half * 32;
    bf16* dst = Vt + ((size_t)((row0 >> 11) * 128 + h) << 11) + (row0 & 2047) + half * 32;
#pragma unroll
    for (int j = 0; j < 4; ++j)
      ((bf16x8*)dst)[j] = ((const bf16x8*)src)[j];
  }
}

// ---------------- flash attention (R8 + Q-hoist + R14 load balance) ---------
// grid 512, 256 thr; 32 q-rows/block; shared 64-wide K/V tile; waves = 2
// row-halves x 2 k-col-halves; 77KB LDS -> 2 blocks/CU; dbuf + raw-barrier +
// vmcnt(8). Q frags preloaded into 16 VGPRs at i==0.
// R14: balanced CU pairing. Causal work KT(qi)=qi/2+1; r<32 -> qi=63-r,
// r>=32 -> qi=r-32 pairs long+short -> every CU carries ~33.5 k-tiles.
__global__ __launch_bounds__(256) void attn_kernel(const bf16* __restrict__ Qb,
                                                   const bf16* __restrict__ Kb,
                                                   const bf16* __restrict__ Vtb,
                                                   float* __restrict__ out) {
  __shared__ __align__(16) char smem[79104];
  bf16* qs = (bf16*)smem;
  bf16* ks = (bf16*)(smem + 8192);
  bf16* vt = (bf16*)(smem + 40960);
  float* Of = (float*)smem;             // epilogue overlay: 2 x 32 x 128 f32
  float* ml = (float*)(smem + 78848);   // 64 f32
  const int t = threadIdx.x, w = t >> 6, lane = t & 63, rl = lane & 15, quad = lane >> 4;
  const int wrow = w >> 1, kh = w & 1;
  const int rank = blockIdx.x >> 3, b = blockIdx.x & 7;
  const int qi = (rank < 32) ? (63 - rank) : (rank - 32);
  const int q0 = qi * 32;
  const size_t base = (size_t)b * TT;
  const int KT = (qi >> 1) + 1;  // 64-wide k-tiles

#pragma unroll
  for (int i2 = 0; i2 < 2; ++i2) {  // stage Q (32 x 128): 2 gll/wave
    int s = w * 2 + i2;
    int row = s * 4 + (lane >> 4);
    int ch = (lane & 15) ^ (row & 15);
    gll16(Qb + ((base + q0 + row) << 7) + ch * 8, qs + s * 512);
  }
  auto stageKV = [&](int slot) {  // always 8 gll/wave (clamped) for exact vmcnt
    int kt = min(slot, KT - 1);
    int bufi = slot & 1;
    bf16* ksb = ks + bufi * 8192;
    bf16* vtb = vt + bufi * 8192;
#pragma unroll
    for (int i2 = 0; i2 < 4; ++i2) {
      int s = w * 4 + i2;
      int rowk = s * 4 + (lane >> 4);
      int chk = (lane & 15) ^ (rowk & 15);
      gll16(Kb + ((base + kt * 64 + rowk) << 7) + chk * 8, ksb + s * 512);
      int rowv = s * 8 + (lane >> 3);
      int chv = (lane & 7) ^ (rowv & 7);
      gll16(Vtb + ((size_t)(b * 128 + rowv) << 11) + kt * 64 + chv * 8, vtb + s * 512);
    }
  };
  stageKV(0);
  stageKV(1);

  f32x4 o[8] = {};
  float lrow[4] = {0.f, 0.f, 0.f, 0.f};
  bf16x8 aq[4];  // loop-invariant Q fragments (hoisted at i==0)
  bf16* psw = (bf16*)(smem + 73728) + w * 640;  // [16][40] per wave

  for (int i = 0; i < KT; ++i) {
    const int cur = i & 1;
    asm volatile("s_waitcnt vmcnt(8)" ::: "memory");
    RAW_BARRIER();
    if (i == 0) {
      const int arow = wrow * 16 + rl;
#pragma unroll
      for (int hc = 0; hc < 4; ++hc)
        aq[hc] = *(const bf16x8*)(qs + arow * 128 + ((((hc << 2) + quad) ^ (arow & 15)) << 3));
    }
    bf16* ksb = ks + cur * 8192;
    bf16* vtb = vt + cur * 8192;
    f32x4 s4[2] = {};
#pragma unroll
    for (int hc = 0; hc < 4; ++hc) {
#pragma unroll
      for (int c = 0; c < 2; ++c) {
        int brow = (kh * 2 + c) * 16 + rl;
        bf16x8 bb = *(const bf16x8*)(ksb + brow * 128 + ((((hc << 2) + quad) ^ (brow & 15)) << 3));
        s4[c] = MFMA16(aq[hc], bb, s4[c]);
      }
    }
    const bool diag = (i == KT - 1);
#pragma unroll
    for (int r = 0; r < 4; ++r) {
      int rloc = quad * 4 + r;
      int rowg = q0 + wrow * 16 + rloc;
      float psum = 0.f;
#pragma unroll
      for (int c = 0; c < 2; ++c) {
        int colg = i * 64 + kh * 32 + c * 16 + rl;
        // fixed-max softmax: scores ~ N(0,~0.6); m=6 is a safe upper bound
        float p = (diag && colg > rowg) ? 0.f : __expf(s4[c][r] * 0.03125f - 6.0f);
        psum += p;
        psw[rloc * 40 + c * 16 + rl] = (bf16)p;
      }
      lrow[r] += psum;
    }
    bf16x8 pa = *(const bf16x8*)(psw + rl * 40 + quad * 8);
#pragma unroll
    for (int ht = 0; ht < 8; ++ht) {
      int brow = ht * 16 + rl;
      bf16x8 bb = *(const bf16x8*)(vtb + brow * 64 + ((((kh << 2) + quad) ^ (brow & 7)) << 3));
      o[ht] = MFMA16(pa, bb, o[ht]);
    }
    RAW_BARRIER();  // all waves done reading buf[cur]
    if (i + 2 <= KT) stageKV(i + 2);
  }

#pragma unroll
  for (int r = 0; r < 4; ++r)
#pragma unroll
    for (int off = 1; off < 16; off <<= 1) lrow[r] += __shfl_xor(lrow[r], off, 64);
  __syncthreads();  // full drain (incl leftover clamped gll); overlay safe
#pragma unroll
  for (int ht = 0; ht < 8; ++ht)
#pragma unroll
    for (int r = 0; r < 4; ++r)
      Of[kh * 4096 + (wrow * 16 + quad * 4 + r) * 128 + ht * 16 + rl] = o[ht][r];
  if (rl == 0)
#pragma unroll
    for (int r = 0; r < 4; ++r) ml[kh * 32 + wrow * 16 + quad * 4 + r] = lrow[r];
  __syncthreads();
#pragma unroll
  for (int r = 0; r < 4; ++r) {
    int rowl = wrow * 16 + quad * 4 + r;
    float inv = 1.f / (ml[rowl] + ml[32 + rowl]);
#pragma unroll
    for (int hh = 0; hh < 4; ++hh) {
      int col = kh * 64 + hh * 16 + rl;
      out[((base + q0 + rowl) << 7) + col] =
          (Of[rowl * 128 + col] + Of[4096 + rowl * 128 + col]) * inv;
    }
  }
}

extern "C" void kernel_launch(void* const* d_in, const int* in_sizes, int n_in,
                              void* d_out, int out_size, void* d_ws, size_t ws_size,
                              hipStream_t stream) {
  const float* x = (const float*)d_in[0];
  const float* Wq = (const float*)d_in[1];
  const float* Wk = (const float*)d_in[2];
  const float* Wv = (const float*)d_in[3];
  float* out = (float*)d_out;
  char* ws = (char*)d_ws;
  // ws: Wt 768KB | Q 4MB | K 4MB | Vt 4MB  (13.4 MB total)
  bf16* Wt = (bf16*)ws;
  bf16* Q = (bf16*)(ws + 786432);
  bf16* K = (bf16*)(ws + 786432 + 4194304);
  bf16* Vt = (bf16*)(ws + 786432 + 2 * 4194304);
  wt_kernel<<<dim3(16, 3), 256, 0, stream>>>(Wq, Wk, Wv, Wt);
  qkv_kernel<<<dim3(512), 256, 0, stream>>>(x, Wt, Q, K, Vt);
  attn_kernel<<<dim3(512), 256, 0, stream>>>(Q, K, Vt, out);
}